// Round 2
// baseline (271.598 us; speedup 1.0000x reference)
//
#include <hip/hip_runtime.h>

// DeformableConv1d: B=32, C=64, L=16384, COUT=64, K=1.
// R4b: f16 pipeline + conflict-free LDS layouts (compile fix: __fp16).
//  - Xt split into hi/lo f16 PLANES [l][c], row stride 36 words,
//    XOR-swizzled at b128-block granularity -> matmul1 B-frag = raw
//    ds_read_b128 (zero v_perm), staging uint2 writes ~conflict-free.
//  - Dedicated gather plane Xg: f16 [c][u], stride 82 halfwords (odd word
//    stride) -> gather reads ~2-way instead of 8-way banked.
//  - Xd (x_deform) reuses the same [l][c] layout WITH the same block-XOR
//    swizzle (write side: block=2wv+(q>>1), word 2(q&1)).
//  - All f32->f16 via v_cvt_pkrtz (1 op / 2 elems) instead of bf16 splits.
//  - matmul1 = 3-pass f16 split, matmul2 = 1-pass f16 (both more accurate
//    than the bf16 versions they replace).
//  - Xd overlays dead XtH region (+1 barrier): LDS 28.9 KB.
// frac computed from p = l + offset in fp32, matching reference exactly.

#define BDIM 256
#define BB   32
#define CC   64
#define LL   16384
#define TL   64                  // l-tile per block
#define HH   8                   // gather halo (offsets max ~3.2)
#define ROWS (TL + 2*HH)         // 80 gather rows in Xg
#define RSW  36                  // Xt/Xd plane row stride (words, 144 B)
#define XGS  82                  // Xg channel stride (halfwords, odd word stride)

typedef __fp16 half_t;
typedef __attribute__((ext_vector_type(2))) __fp16 h2;
typedef __attribute__((ext_vector_type(8))) __fp16 h8;
typedef __attribute__((ext_vector_type(4))) float f4;

union H2U { h2 h; unsigned u; };
union H8U { unsigned u[4]; h8 v; };

static __device__ __forceinline__ unsigned pk(float a, float b) {
    H2U r; r.h = __builtin_amdgcn_cvt_pkrtz(a, b); return r.u;
}

// split A-frag (weights) from global fp32: lane holds W[row][k0..k0+7]
static __device__ __forceinline__ void load_a_split(const float* __restrict__ wp,
                                                    int row, int ks, int q,
                                                    h8* ahi, h8* alo) {
    const float* base = wp + row * 64 + ks * 32 + q * 8;
    float4 w0 = *(const float4*)base;
    float4 w1 = *(const float4*)(base + 4);
    float v[8] = {w0.x, w0.y, w0.z, w0.w, w1.x, w1.y, w1.z, w1.w};
    H8U h, l;
    #pragma unroll
    for (int p = 0; p < 4; ++p) {
        H2U hh; hh.h = __builtin_amdgcn_cvt_pkrtz(v[2*p], v[2*p+1]);
        h.u[p] = hh.u;
        l.u[p] = pk(v[2*p] - (float)hh.h[0], v[2*p+1] - (float)hh.h[1]);
    }
    *ahi = h.v; *alo = l.v;
}

static __device__ __forceinline__ h8 load_a_f16(const float* __restrict__ wp,
                                                int row, int ks, int q) {
    const float* base = wp + row * 64 + ks * 32 + q * 8;
    float4 w0 = *(const float4*)base;
    float4 w1 = *(const float4*)(base + 4);
    float v[8] = {w0.x, w0.y, w0.z, w0.w, w1.x, w1.y, w1.z, w1.w};
    H8U r;
    #pragma unroll
    for (int p = 0; p < 4; ++p) r.u[p] = pk(v[2*p], v[2*p+1]);
    return r.v;
}

__global__ __launch_bounds__(BDIM)
void deform_conv1d_r4(const float* __restrict__ x,
                      const float* __restrict__ offw,
                      const float* __restrict__ offb,
                      const float* __restrict__ regw,
                      const float* __restrict__ regb,
                      float* __restrict__ out) {
    // carve: XtH (9216 B, later overlaid by Xd) | XtL (9216 B) | Xg (10496 B)
    __shared__ __align__(16) unsigned char smem[9216 + 9216 + 10496];
    unsigned* XtH = (unsigned*)smem;
    unsigned* XtL = (unsigned*)(smem + 9216);
    half_t*   Xg  = (half_t*)(smem + 18432);
    unsigned* XdW = (unsigned*)smem;            // overlay XtH (after barrier)

    const int tid = threadIdx.x;
    const int bx  = blockIdx.x;
    const int lg0 = bx * TL;
    const int b   = blockIdx.y;
    const size_t xb = (size_t)b * CC * LL;

    // ---------------- stage x -> Xg [c][u] f16  and  XtH/XtL [l][c] --------
    if (bx >= 1 && bx <= (LL / TL) - 2) {
        for (int i = tid; i < 320; i += BDIM) {      // 16 cb x 20 lb of 4x4
            int cb = i / 20, lb = i - cb * 20;
            int c0 = cb * 4;
            int l0 = lg0 - HH + lb * 4;              // >= 56, +3 <= L-1
            const float* pp = x + xb + (size_t)c0 * LL + l0;
            float4 v0 = *(const float4*)(pp);
            float4 v1 = *(const float4*)(pp + LL);
            float4 v2 = *(const float4*)(pp + 2 * LL);
            float4 v3 = *(const float4*)(pp + 3 * LL);
            // Xg: word index (82*c + 4*lb)/2 = 41*c + 2*lb
            unsigned* gw = (unsigned*)Xg;
            int wi = 41 * c0 + 2 * lb;
            gw[wi]       = pk(v0.x, v0.y); gw[wi + 1]   = pk(v0.z, v0.w);
            gw[wi + 41]  = pk(v1.x, v1.y); gw[wi + 42]  = pk(v1.z, v1.w);
            gw[wi + 82]  = pk(v2.x, v2.y); gw[wi + 83]  = pk(v2.z, v2.w);
            gw[wi + 123] = pk(v3.x, v3.y); gw[wi + 124] = pk(v3.z, v3.w);
            // Xt planes: rows 0..63 only (lb in [2,18)), block-XOR swizzle
            if (lb >= 2 && lb < 18) {
                int m = lb - 2;                      // row>>2 for this tile
                float e0[4] = {v0.x, v0.y, v0.z, v0.w};
                float e1[4] = {v1.x, v1.y, v1.z, v1.w};
                float e2[4] = {v2.x, v2.y, v2.z, v2.w};
                float e3[4] = {v3.x, v3.y, v3.z, v3.w};
                int blkw  = (cb >> 1) ^ (m & 7);     // swizzled b128 block
                int wbase = (4 * m) * RSW + (blkw << 2) + 2 * (cb & 1);
                #pragma unroll
                for (int rl = 0; rl < 4; ++rl) {
                    float a = e0[rl], bb = e1[rl], cc = e2[rl], dd = e3[rl];
                    H2U h0, h1;
                    h0.h = __builtin_amdgcn_cvt_pkrtz(a, bb);
                    h1.h = __builtin_amdgcn_cvt_pkrtz(cc, dd);
                    int widx = wbase + rl * RSW;
                    uint2 hw; hw.x = h0.u; hw.y = h1.u;
                    *(uint2*)&XtH[widx] = hw;
                    uint2 lw;
                    lw.x = pk(a  - (float)h0.h[0], bb - (float)h0.h[1]);
                    lw.y = pk(cc - (float)h1.h[0], dd - (float)h1.h[1]);
                    *(uint2*)&XtL[widx] = lw;
                }
            }
        }
    } else {                                          // edge blocks: clamped
        for (int i = tid; i < ROWS * CC; i += BDIM) {
            int r = i >> 6, c = i & 63;
            int g = min(max(lg0 - HH + r, 0), LL - 1);
            float v = x[xb + (size_t)c * LL + g];
            H2U hv; hv.h = __builtin_amdgcn_cvt_pkrtz(v, 0.0f);
            Xg[c * XGS + r] = hv.h[0];
            int row = r - HH;
            if (row >= 0 && row < TL) {
                int blkw = (c >> 3) ^ ((row >> 2) & 7);
                int widx = row * RSW + (blkw << 2) + ((c >> 1) & 3);
                float lo = v - (float)hv.h[0];
                H2U lv; lv.h = __builtin_amdgcn_cvt_pkrtz(lo, 0.0f);
                ((half_t*)XtH)[2 * widx + (c & 1)] = hv.h[0];
                ((half_t*)XtL)[2 * widx + (c & 1)] = lv.h[0];
            }
        }
    }

    const int wv   = tid >> 6;       // wave -> output-row tile [16wv,16wv+16)
    const int lane = tid & 63;
    const int q    = lane >> 4;
    const int n    = lane & 15;

    // A1 frags + bias: global-only, issue before the barrier
    h8 ahi[2], alo[2];
    load_a_split(offw, 16 * wv + n, 0, q, &ahi[0], &alo[0]);
    load_a_split(offw, 16 * wv + n, 1, q, &ahi[1], &alo[1]);
    f4 acc[4];
    {
        float4 bo = *(const float4*)(offb + 16 * wv + 4 * q);
        #pragma unroll
        for (int nt = 0; nt < 4; ++nt) acc[nt] = (f4){bo.x, bo.y, bo.z, bo.w};
    }
    __syncthreads();

    // ------------- matmul 1: offsets = Wo * x + bo  (3-pass f16 split) ------
    #pragma unroll
    for (int nt = 0; nt < 4; ++nt) {
        const int row = 16 * nt + n;
        const int rb  = row * RSW;
        const int sb  = (row >> 2) & 7;
        #pragma unroll
        for (int ks = 0; ks < 2; ++ks) {
            int blk = (4 * ks + q) ^ sb;
            h8 bh = *(const h8*)&XtH[rb + (blk << 2)];
            h8 bl = *(const h8*)&XtL[rb + (blk << 2)];
            acc[nt] = __builtin_amdgcn_mfma_f32_16x16x32_f16(ahi[ks], bh, acc[nt], 0, 0, 0);
            acc[nt] = __builtin_amdgcn_mfma_f32_16x16x32_f16(ahi[ks], bl, acc[nt], 0, 0, 0);
            acc[nt] = __builtin_amdgcn_mfma_f32_16x16x32_f16(alo[ks], bh, acc[nt], 0, 0, 0);
        }
    }

    // ------------- gather + lerp (acc := x_deform), ref-exact frac ----------
    #pragma unroll
    for (int nt = 0; nt < 4; ++nt) {
        const int l = lg0 + 16 * nt + n;
        #pragma unroll
        for (int reg = 0; reg < 4; ++reg) {
            const int c = 16 * wv + 4 * q + reg;      // C/D row
            float o  = acc[nt][reg];
            float p  = (float)l + o;                  // same fp32 add as ref
            p = __builtin_amdgcn_fmed3f(p, 0.0f, (float)(LL - 1));
            float of = floorf(p);
            float fr = p - of;
            int idx  = (int)of;
            int u    = idx - lg0 + HH;
            float x0, x1;
            if ((unsigned)u <= (unsigned)(ROWS - 2)) {
                const half_t* gp = Xg + c * XGS + u;
                x0 = (float)gp[0];
                x1 = (float)gp[1];
            } else {                                   // |off|>8: ~never
                const float* xr = x + xb + (size_t)c * LL;
                x0 = xr[idx];
                x1 = xr[idx + (fr > 0.0f ? 1 : 0)];
            }
            acc[nt][reg] = x0 + fr * (x1 - x0);
        }
    }

    __syncthreads();                  // all Xt reads done; Xd overlays XtH

    // ------------- x_deform -> Xd[l][c] f16, block-XOR swizzled -------------
    #pragma unroll
    for (int nt = 0; nt < 4; ++nt) {
        const int row = 16 * nt + n;
        const int sb  = (row >> 2) & 7;
        const int bw  = (2 * wv + (q >> 1)) ^ sb;
        uint2 pw;
        pw.x = pk(acc[nt][0], acc[nt][1]);
        pw.y = pk(acc[nt][2], acc[nt][3]);
        *(uint2*)&XdW[row * RSW + (bw << 2) + 2 * (q & 1)] = pw;
    }

    // A2 frags + bias while waiting
    h8 a2[2];
    a2[0] = load_a_f16(regw, 16 * wv + n, 0, q);
    a2[1] = load_a_f16(regw, 16 * wv + n, 1, q);
    {
        float4 br = *(const float4*)(regb + 16 * wv + 4 * q);
        #pragma unroll
        for (int nt = 0; nt < 4; ++nt) acc[nt] = (f4){br.x, br.y, br.z, br.w};
    }
    __syncthreads();

    // ------------- matmul 2: out = Wr * x_deform + br  (1-pass f16) ---------
    #pragma unroll
    for (int nt = 0; nt < 4; ++nt) {
        const int row = 16 * nt + n;
        const int sb  = (row >> 2) & 7;
        #pragma unroll
        for (int ks = 0; ks < 2; ++ks) {
            int blk = (4 * ks + q) ^ sb;
            h8 bv = *(const h8*)&XdW[row * RSW + (blk << 2)];
            acc[nt] = __builtin_amdgcn_mfma_f32_16x16x32_f16(a2[ks], bv, acc[nt], 0, 0, 0);
        }
    }

    // ------------- store ----------------------------------------------------
    float* op = out + (size_t)b * CC * LL;
    #pragma unroll
    for (int nt = 0; nt < 4; ++nt) {
        #pragma unroll
        for (int reg = 0; reg < 4; ++reg) {
            op[(size_t)(16 * wv + 4 * q + reg) * LL + lg0 + 16 * nt + n] = acc[nt][reg];
        }
    }
}

extern "C" void kernel_launch(void* const* d_in, const int* in_sizes, int n_in,
                              void* d_out, int out_size, void* d_ws, size_t ws_size,
                              hipStream_t stream) {
    const float* x    = (const float*)d_in[0];   // [32,64,16384]
    const float* offw = (const float*)d_in[1];   // [64,64,1]
    const float* offb = (const float*)d_in[2];   // [64]
    const float* regw = (const float*)d_in[3];   // [64,64,1]
    const float* regb = (const float*)d_in[4];   // [64]
    float* out = (float*)d_out;                  // [32,64,16384]

    dim3 grid(LL / TL, BB);
    deform_conv1d_r4<<<grid, dim3(BDIM), 0, stream>>>(x, offw, offb, regw, regb, out);
}

// Round 4
// 256.848 us; speedup vs baseline: 1.0574x; 1.0574x over previous
//
#include <hip/hip_runtime.h>

// DeformableConv1d: B=32, C=64, L=16384, COUT=64, K=1.
// R5 (resubmit; previous round was an infra failure, kernel never ran):
// occupancy-first restructure (R4b was latency-bound at 5 blocks/CU,
// all pipes <30% busy, occupancy 36%).
//  - ONE staged x plane XtH: f16 [row][c], 72 rows (halo HH=4), row stride
//    36 words, XOR-swizzled b128 blocks. Serves BOTH matmul1 B-frags
//    (raw ds_read_b128) AND the gather (per-element u16 reads, ~2-way).
//  - matmul1 = 2-pass split-WEIGHT f16 (w_hi*x + w_lo*x): offset error
//    ~1.7e-4 std from f16(x) only.
//  - Xd own plane (9.2 KB) -> only 2 barriers.
//  - LDS 19.6 KB -> 8 blocks/CU (was 5), occupancy cap 100%.
//  - |offset|>4 falls back to global x (P ~ 4e-12 per elem).
// frac computed from p = l + offset in fp32, matching reference exactly.

#define BDIM 256
#define BB   32
#define CC   64
#define LL   16384
#define TL   64                  // l-tile per block
#define HH   4                   // gather halo (offset std 0.577 -> 6.9 sigma)
#define ROWS (TL + 2*HH)         // 72 staged rows
#define RSW  36                  // row stride (words, 144 B)
#define RSH  72                  // row stride (halfwords)

typedef __fp16 half_t;
typedef __attribute__((ext_vector_type(2))) __fp16 h2;
typedef __attribute__((ext_vector_type(8))) __fp16 h8;
typedef __attribute__((ext_vector_type(4))) float f4;

union H2U { h2 h; unsigned u; };
union H8U { unsigned u[4]; h8 v; };

static __device__ __forceinline__ unsigned pk(float a, float b) {
    H2U r; r.h = __builtin_amdgcn_cvt_pkrtz(a, b); return r.u;
}

// split A-frag (weights) from global fp32: lane holds W[row][k0..k0+7]
static __device__ __forceinline__ void load_a_split(const float* __restrict__ wp,
                                                    int row, int ks, int q,
                                                    h8* ahi, h8* alo) {
    const float* base = wp + row * 64 + ks * 32 + q * 8;
    float4 w0 = *(const float4*)base;
    float4 w1 = *(const float4*)(base + 4);
    float v[8] = {w0.x, w0.y, w0.z, w0.w, w1.x, w1.y, w1.z, w1.w};
    H8U h, l;
    #pragma unroll
    for (int p = 0; p < 4; ++p) {
        H2U hh; hh.h = __builtin_amdgcn_cvt_pkrtz(v[2*p], v[2*p+1]);
        h.u[p] = hh.u;
        l.u[p] = pk(v[2*p] - (float)hh.h[0], v[2*p+1] - (float)hh.h[1]);
    }
    *ahi = h.v; *alo = l.v;
}

static __device__ __forceinline__ h8 load_a_f16(const float* __restrict__ wp,
                                                int row, int ks, int q) {
    const float* base = wp + row * 64 + ks * 32 + q * 8;
    float4 w0 = *(const float4*)base;
    float4 w1 = *(const float4*)(base + 4);
    float v[8] = {w0.x, w0.y, w0.z, w0.w, w1.x, w1.y, w1.z, w1.w};
    H8U r;
    #pragma unroll
    for (int p = 0; p < 4; ++p) r.u[p] = pk(v[2*p], v[2*p+1]);
    return r.v;
}

__global__ __launch_bounds__(BDIM)
void deform_conv1d_r5(const float* __restrict__ x,
                      const float* __restrict__ offw,
                      const float* __restrict__ offb,
                      const float* __restrict__ regw,
                      const float* __restrict__ regb,
                      float* __restrict__ out) {
    // XtH: 72 rows x 36 words = 10368 B ; Xd: 64 rows x 36 words = 9216 B
    __shared__ __align__(16) unsigned char smem[10368 + 9216];
    unsigned* XtH = (unsigned*)smem;
    unsigned* XdW = (unsigned*)(smem + 10368);
    half_t*   XtHh = (half_t*)smem;
    half_t*   Xdh  = (half_t*)(smem + 10368);
    (void)Xdh;

    const int tid = threadIdx.x;
    const int bx  = blockIdx.x;
    const int lg0 = bx * TL;
    const int b   = blockIdx.y;
    const size_t xb = (size_t)b * CC * LL;

    // ---------------- stage x -> XtH [row][c] f16, block-XOR swizzled ------
    if (bx >= 1 && bx <= (LL / TL) - 2) {
        for (int i = tid; i < 288; i += BDIM) {      // 16 cb x 18 lb of 4x4
            int cb = i / 18, lb = i - cb * 18;
            int c0 = cb * 4;
            int l0 = lg0 - HH + lb * 4;              // >= 60, +3 <= L-62+3
            const float* pp = x + xb + (size_t)c0 * LL + l0;
            float4 v0 = *(const float4*)(pp);
            float4 v1 = *(const float4*)(pp + LL);
            float4 v2 = *(const float4*)(pp + 2 * LL);
            float4 v3 = *(const float4*)(pp + 3 * LL);
            float e0[4] = {v0.x, v0.y, v0.z, v0.w};  // e_j[rl] = x[c0+j][l0+rl]
            float e1[4] = {v1.x, v1.y, v1.z, v1.w};
            float e2[4] = {v2.x, v2.y, v2.z, v2.w};
            float e3[4] = {v3.x, v3.y, v3.z, v3.w};
            int blkw  = (cb >> 1) ^ (lb & 7);        // swizzled b128 block
            int wbase = (4 * lb) * RSW + (blkw << 2) + 2 * (cb & 1);
            #pragma unroll
            for (int rl = 0; rl < 4; ++rl) {
                uint2 hw;
                hw.x = pk(e0[rl], e1[rl]);
                hw.y = pk(e2[rl], e3[rl]);
                *(uint2*)&XtH[wbase + rl * RSW] = hw;
            }
        }
    } else {                                          // edge blocks: clamped
        for (int i = tid; i < ROWS * CC; i += BDIM) {
            int r = i >> 6, c = i & 63;
            int g = min(max(lg0 - HH + r, 0), LL - 1);
            float v = x[xb + (size_t)c * LL + g];
            int blk = (c >> 3) ^ ((r >> 2) & 7);
            XtHh[r * RSH + (blk << 3) + (c & 7)] = (half_t)v;
        }
    }

    const int wv   = tid >> 6;       // wave -> output-row tile [16wv,16wv+16)
    const int lane = tid & 63;
    const int q    = lane >> 4;
    const int n    = lane & 15;

    // A1 frags + bias: global-only, issue before the barrier
    h8 ahi[2], alo[2];
    load_a_split(offw, 16 * wv + n, 0, q, &ahi[0], &alo[0]);
    load_a_split(offw, 16 * wv + n, 1, q, &ahi[1], &alo[1]);
    f4 acc[4];
    {
        float4 bo = *(const float4*)(offb + 16 * wv + 4 * q);
        #pragma unroll
        for (int nt = 0; nt < 4; ++nt) acc[nt] = (f4){bo.x, bo.y, bo.z, bo.w};
    }
    __syncthreads();

    // ------------- matmul 1: offsets = Wo*x + bo (2-pass split weight) ------
    #pragma unroll
    for (int nt = 0; nt < 4; ++nt) {
        const int r  = 16 * nt + n + HH;              // staged row
        const int rb = r * RSW;
        const int sb = (r >> 2) & 7;
        #pragma unroll
        for (int ks = 0; ks < 2; ++ks) {
            int blk = (4 * ks + q) ^ sb;
            h8 bv = *(const h8*)&XtH[rb + (blk << 2)];
            acc[nt] = __builtin_amdgcn_mfma_f32_16x16x32_f16(ahi[ks], bv, acc[nt], 0, 0, 0);
            acc[nt] = __builtin_amdgcn_mfma_f32_16x16x32_f16(alo[ks], bv, acc[nt], 0, 0, 0);
        }
    }

    // ------------- gather + lerp (acc := x_deform), ref-exact frac ----------
    #pragma unroll
    for (int nt = 0; nt < 4; ++nt) {
        const int l = lg0 + 16 * nt + n;
        #pragma unroll
        for (int reg = 0; reg < 4; ++reg) {
            const int c = 16 * wv + 4 * q + reg;      // C/D row
            float o  = acc[nt][reg];
            float p  = (float)l + o;                  // same fp32 add as ref
            p = __builtin_amdgcn_fmed3f(p, 0.0f, (float)(LL - 1));
            float of = floorf(p);
            float fr = p - of;
            int idx  = (int)of;
            int u    = idx - lg0 + HH;
            float x0, x1;
            if ((unsigned)u <= (unsigned)(ROWS - 2)) {
                int b0 = (c >> 3) ^ ((u >> 2) & 7);
                int b1 = (c >> 3) ^ (((u + 1) >> 2) & 7);
                x0 = (float)XtHh[u * RSH + (b0 << 3) + (c & 7)];
                x1 = (float)XtHh[(u + 1) * RSH + (b1 << 3) + (c & 7)];
            } else {                                   // |off|>4: ~never
                const float* xr = x + xb + (size_t)c * LL;
                x0 = xr[idx];
                x1 = xr[idx + (fr > 0.0f ? 1 : 0)];
            }
            acc[nt][reg] = x0 + fr * (x1 - x0);
        }
    }

    // ------------- x_deform -> Xd[l][c] f16, block-XOR swizzled -------------
    #pragma unroll
    for (int nt = 0; nt < 4; ++nt) {
        const int row = 16 * nt + n;
        const int sb  = (row >> 2) & 7;
        const int bw  = (2 * wv + (q >> 1)) ^ sb;
        uint2 pw;
        pw.x = pk(acc[nt][0], acc[nt][1]);
        pw.y = pk(acc[nt][2], acc[nt][3]);
        *(uint2*)&XdW[row * RSW + (bw << 2) + 2 * (q & 1)] = pw;
    }

    // A2 frags + bias while waiting
    h8 a2[2];
    a2[0] = load_a_f16(regw, 16 * wv + n, 0, q);
    a2[1] = load_a_f16(regw, 16 * wv + n, 1, q);
    {
        float4 br = *(const float4*)(regb + 16 * wv + 4 * q);
        #pragma unroll
        for (int nt = 0; nt < 4; ++nt) acc[nt] = (f4){br.x, br.y, br.z, br.w};
    }
    __syncthreads();

    // ------------- matmul 2: out = Wr * x_deform + br  (1-pass f16) ---------
    #pragma unroll
    for (int nt = 0; nt < 4; ++nt) {
        const int row = 16 * nt + n;
        const int sb  = (row >> 2) & 7;
        #pragma unroll
        for (int ks = 0; ks < 2; ++ks) {
            int blk = (4 * ks + q) ^ sb;
            h8 bv = *(const h8*)&XdW[row * RSW + (blk << 2)];
            acc[nt] = __builtin_amdgcn_mfma_f32_16x16x32_f16(a2[ks], bv, acc[nt], 0, 0, 0);
        }
    }

    // ------------- store ----------------------------------------------------
    float* op = out + (size_t)b * CC * LL;
    #pragma unroll
    for (int nt = 0; nt < 4; ++nt) {
        #pragma unroll
        for (int reg = 0; reg < 4; ++reg) {
            op[(size_t)(16 * wv + 4 * q + reg) * LL + lg0 + 16 * nt + n] = acc[nt][reg];
        }
    }
}

extern "C" void kernel_launch(void* const* d_in, const int* in_sizes, int n_in,
                              void* d_out, int out_size, void* d_ws, size_t ws_size,
                              hipStream_t stream) {
    const float* x    = (const float*)d_in[0];   // [32,64,16384]
    const float* offw = (const float*)d_in[1];   // [64,64,1]
    const float* offb = (const float*)d_in[2];   // [64]
    const float* regw = (const float*)d_in[3];   // [64,64,1]
    const float* regb = (const float*)d_in[4];   // [64]
    float* out = (float*)d_out;                  // [32,64,16384]

    dim3 grid(LL / TL, BB);
    deform_conv1d_r5<<<grid, dim3(BDIM), 0, stream>>>(x, offw, offb, regw, regb, out);
}